// Round 8
// baseline (1887.042 us; speedup 1.0000x reference)
//
#include <hip/hip_runtime.h>
#include <hip/hip_bf16.h>

#define DIMN  256
#define NOBJ  16384
#define NPAIR 131072
#define NINC  (2 * NPAIR)
#define NPRT  (NPAIR / 32)          // 4096 pred tiles of 32 rows
#define NTILE (NPRT + NOBJ / 32)    // + 512 obj tiles = 4608 = 256 * 18

typedef float  floatx4 __attribute__((ext_vector_type(4)));
typedef __bf16 bf16x8  __attribute__((ext_vector_type(8)));
typedef unsigned int u32;

static __device__ __forceinline__ unsigned f2bf(float f) {
  unsigned u = __builtin_bit_cast(unsigned, f);
  u += 0x7FFFu + ((u >> 16) & 1u);          // round-to-nearest-even
  return u >> 16;
}
static __device__ __forceinline__ float sigmoidf_(float x) {
  return 1.0f / (1.0f + __expf(-x));
}
static __device__ __forceinline__ float tanhf_(float x) {
  return 1.0f - 2.0f / (1.0f + __expf(2.0f * x));
}
static __device__ __forceinline__ float dot4(float4 a, float4 b) {
  return a.x*b.x + a.y*b.y + a.z*b.z + a.w*b.w;
}
static __device__ __forceinline__ float4 relu4(float4 a) {
  float4 r; r.x = fmaxf(a.x,0.f); r.y = fmaxf(a.y,0.f);
  r.z = fmaxf(a.z,0.f); r.w = fmaxf(a.w,0.f); return r;
}
static __device__ __forceinline__ floatx4 mfma16(bf16x8 a, bf16x8 b, floatx4 c) {
  return __builtin_amdgcn_mfma_f32_16x16x32_bf16(a, b, c, 0, 0, 0);
}
// async global->LDS, 16 B per lane: LDS dest = uniform base + lane*16 (linear),
// global src = per-lane. Counted in vmcnt; __syncthreads() drains it.
typedef const __attribute__((address_space(1))) u32* gas_ptr;
typedef __attribute__((address_space(3))) u32*       las_ptr;
static __device__ __forceinline__ void gload16(const void* g, void* l) {
  __builtin_amdgcn_global_load_lds((gas_ptr)g, (las_ptr)l, 16, 0, 0);
}

// ---------------------------------------------------------------------------
// weight fp32 -> bf16, repacked into fragment order [ct][kc][s][lane]:
//   frag index i = ((ct*8 + kc)*6 + s)*64 + lane      (49152 frags of 16 B)
//   kc-major-over-s: the 6 per-kc B loads sit at {0..5}*1KB from one base ->
//   foldable into the signed 13-bit global-load immediate.
__global__ __launch_bounds__(256) void conv_w(const float* __restrict__ wih,
                                              const float* __restrict__ whh,
                                              unsigned short* __restrict__ out) {
  const int i    = blockIdx.x * 256 + threadIdx.x;   // 0..49151
  const int lane = i & 63;
  const int t    = i >> 6;           // 0..767
  const int s    = t % 6;
  const int u    = t / 6;            // 0..127
  const int kc   = u & 7;
  const int ct   = u >> 3;
  const int col  = ct * 16 + (lane & 15);
  const int k0   = kc * 32 + (lane >> 4) * 8;
  const float* src = (s < 3) ? (wih + ((size_t)(s * 256 + col)) * 256 + k0)
                             : (whh + ((size_t)((s - 3) * 256 + col)) * 256 + k0);
  float4 a = ((const float4*)src)[0];
  float4 b = ((const float4*)src)[1];
  uint4 pk;
  pk.x = f2bf(a.x) | (f2bf(a.y) << 16);
  pk.y = f2bf(a.z) | (f2bf(a.w) << 16);
  pk.z = f2bf(b.x) | (f2bf(b.y) << 16);
  pk.w = f2bf(b.z) | (f2bf(b.w) << 16);
  *(uint4*)(out + (size_t)i * 8) = pk;
}

// ---------------------------------------------------------------------------
// fp32 rows -> bf16 pre-swizzled rows (GRU H staging format). One wave/row.
__global__ __launch_bounds__(256) void conv_h(const float* __restrict__ src,
                                              unsigned short* __restrict__ dst) {
  const int wave = threadIdx.x >> 6, lane = threadIdx.x & 63;
  const int r = blockIdx.x * 4 + wave;
  float4 v = ((const float4*)(src + (size_t)r * DIMN))[lane];
  ushort4 pk;
  pk.x = (unsigned short)f2bf(v.x); pk.y = (unsigned short)f2bf(v.y);
  pk.z = (unsigned short)f2bf(v.z); pk.w = (unsigned short)f2bf(v.w);
  *(ushort4*)(dst + (size_t)r * DIMN + ((lane >> 1) ^ (r & 7)) * 8 + (lane & 1) * 4) = pk;
}

// ---------------------------------------------------------------------------
// CSR build: histogram -> scan -> scatter.
__global__ __launch_bounds__(256) void hist_kernel(const int* __restrict__ pairs,
                                                   int* __restrict__ cnt) {
  int i = blockIdx.x * 256 + threadIdx.x;
  atomicAdd(&cnt[pairs[i]], 1);
}

__global__ __launch_bounds__(1024) void scan_kernel(const int* __restrict__ cnt,
                                                    int* __restrict__ row_start,
                                                    int* __restrict__ cursor) {
  __shared__ int sums[1024];
  const int t = threadIdx.x;
  const int base = t * 16;
  int local[16];
  int s = 0;
  #pragma unroll
  for (int i = 0; i < 16; i++) { local[i] = s; s += cnt[base + i]; }
  sums[t] = s;
  __syncthreads();
  for (int off = 1; off < 1024; off <<= 1) {
    int v = (t >= off) ? sums[t - off] : 0;
    __syncthreads();
    sums[t] += v;
    __syncthreads();
  }
  const int prefix = (t == 0) ? 0 : sums[t - 1];
  #pragma unroll
  for (int i = 0; i < 16; i++) {
    int v = prefix + local[i];
    row_start[base + i] = v;
    cursor[base + i] = v;
  }
  if (t == 1023) row_start[16384] = sums[1023];
}

__global__ __launch_bounds__(256) void scatter_kernel(const int* __restrict__ pairs,
                                                      int* __restrict__ cursor,
                                                      int* __restrict__ entries) {
  int i = blockIdx.x * 256 + threadIdx.x;
  int pos = atomicAdd(&cursor[pairs[i]], 1);
  entries[pos] = i;
}

// ---------------------------------------------------------------------------
// Gate kernel: one wave per pair. Writes gbuf, xg (bf16 swz) AND hp = bf16
// swizzled copy of the x_pred row it already loaded (free emit: the pred-GRU
// H-staging input; identical RNE convert to the old in-GRU path).
__global__ __launch_bounds__(256) void gate_kernel(
    const float* __restrict__ xobj, const float* __restrict__ xpred,
    const int* __restrict__ pairs,
    const float* __restrict__ w_e2v, const float* __restrict__ b_e2v,
    const float* __restrict__ w_v2e, const float* __restrict__ b_v2e,
    float* __restrict__ gbuf, unsigned short* __restrict__ xg,
    unsigned short* __restrict__ hp)
{
  const int wave = threadIdx.x >> 6;
  const int lane = threadIdx.x & 63;
  const int p = blockIdx.x * 4 + wave;
  const int s = pairs[2*p], o = pairs[2*p+1];

  float4 vp = ((const float4*)(xpred + (size_t)p*DIMN))[lane];
  float4 vs = ((const float4*)(xobj  + (size_t)s*DIMN))[lane];
  float4 vo = ((const float4*)(xobj  + (size_t)o*DIMN))[lane];
  float4 we0 = ((const float4*)w_e2v)[lane];
  float4 we1 = ((const float4*)w_e2v)[64 + lane];
  float4 wv0 = ((const float4*)w_v2e)[lane];
  float4 wv1 = ((const float4*)w_v2e)[64 + lane];

  float4 rp = relu4(vp), rs = relu4(vs), ro = relu4(vo);
  float t0 = dot4(rs, we0);
  float t1 = dot4(ro, we0);
  float t2 = dot4(rp, we1);
  float t3 = dot4(rp, wv0);
  float t4 = dot4(rs, wv1);
  float t5 = dot4(ro, wv1);
  #pragma unroll
  for (int off = 32; off >= 1; off >>= 1) {
    t0 += __shfl_xor(t0, off); t1 += __shfl_xor(t1, off);
    t2 += __shfl_xor(t2, off); t3 += __shfl_xor(t3, off);
    t4 += __shfl_xor(t4, off); t5 += __shfl_xor(t5, off);
  }
  const float be = b_e2v[0], bv = b_v2e[0];
  const float g_s  = sigmoidf_(t0 + t2 + be);
  const float g_o  = sigmoidf_(t1 + t2 + be);
  const float g_sp = sigmoidf_(t3 + t4 + bv);
  const float g_op = sigmoidf_(t3 + t5 + bv);

  // lane l owns bf16 elems [4l,4l+4) = half of 16B chunk (l>>1);
  // swizzled ushort offset = ((l>>1) ^ (p&7))*8 + (l&1)*4.
  const int swo = ((lane >> 1) ^ (p & 7)) * 8 + (lane & 1) * 4;
  ushort4 pk;
  pk.x = (unsigned short)f2bf(vs.x*g_sp + vo.x*g_op);
  pk.y = (unsigned short)f2bf(vs.y*g_sp + vo.y*g_op);
  pk.z = (unsigned short)f2bf(vs.z*g_sp + vo.z*g_op);
  pk.w = (unsigned short)f2bf(vs.w*g_sp + vo.w*g_op);
  *(ushort4*)(xg + (size_t)p * DIMN + swo) = pk;

  ushort4 ph;
  ph.x = (unsigned short)f2bf(vp.x); ph.y = (unsigned short)f2bf(vp.y);
  ph.z = (unsigned short)f2bf(vp.z); ph.w = (unsigned short)f2bf(vp.w);
  *(ushort4*)(hp + (size_t)p * DIMN + swo) = ph;

  if (lane == 0) { gbuf[2*p] = g_s; gbuf[2*p+1] = g_o; }
}

// ---------------------------------------------------------------------------
// Gather segment-sum: one wave per object; writes msg bf16 pre-swizzled.
__global__ __launch_bounds__(256) void gather_kernel(
    const float* __restrict__ xpred, const float* __restrict__ gbuf,
    const int* __restrict__ row_start, const int* __restrict__ entries,
    unsigned short* __restrict__ msg)
{
  const int wave = threadIdx.x >> 6;
  const int lane = threadIdx.x & 63;
  const int obj = blockIdx.x * 4 + wave;
  const int s0 = row_start[obj], s1 = row_start[obj + 1];

  float4 acc = {0.f, 0.f, 0.f, 0.f};
  int inc = (s0 < s1) ? entries[s0] : 0;
  for (int e = s0; e < s1; e++) {
    int ninc = (e + 1 < s1) ? entries[e + 1] : 0;   // prefetch next index
    float g = gbuf[inc];
    float4 v = ((const float4*)(xpred + (size_t)(inc >> 1) * DIMN))[lane];
    acc.x += g * v.x; acc.y += g * v.y; acc.z += g * v.z; acc.w += g * v.w;
    inc = ninc;
  }
  ushort4 pk;
  pk.x = (unsigned short)f2bf(acc.x);
  pk.y = (unsigned short)f2bf(acc.y);
  pk.z = (unsigned short)f2bf(acc.z);
  pk.w = (unsigned short)f2bf(acc.w);
  *(ushort4*)(msg + (size_t)obj * DIMN +
              ((lane >> 1) ^ (obj & 7)) * 8 + (lane & 1) * 4) = pk;
}

// ---------------------------------------------------------------------------
// Fused GRU v9: persistent double-buffered. 256 blocks x 1024 thr (16 waves);
// each block owns 18 tiles of 32 rows x 256 cols (4096 pred + 512 obj tiles
// merged). Both X and H arrive as producer-pre-swizzled bf16, staged by pure
// global_load_lds (2/wave/tile, zero staging VALU/regs). Per tile: issue
// stage(t+1) into the other buffer -> K-loop(t) -> epilogue(t) -> barrier.
// HBM staging hides under compute. acc = 32 AGPR (32-row tile) + ~65 VGPR
// ~= 100 regs/wave, ~28 regs under the 1024-thr 128 cap (not edge-designed).
__global__ __launch_bounds__(1024) void gru_kernel(
    const unsigned short* __restrict__ Xp, const unsigned short* __restrict__ Hbp,
    const float* __restrict__ Hfp, float* __restrict__ OUTp,
    const unsigned short* __restrict__ Xo, const unsigned short* __restrict__ Hbo,
    const float* __restrict__ Hfo, float* __restrict__ OUTo,
    const unsigned short* __restrict__ Wpk,
    const float* __restrict__ b_ih, const float* __restrict__ b_hh)
{
  __shared__ unsigned short Xs0[32 * 256], Hs0[32 * 256];   // 16 KB each
  __shared__ unsigned short Xs1[32 * 256], Hs1[32 * 256];   // total 64 KB

  const int tid  = threadIdx.x;
  const int lane = tid & 63;
  const int wave = tid >> 6;          // 0..15 = col tile (ct)
  const int quad = lane >> 4;
  const int l16  = lane & 15;
  const int col  = wave * 16 + l16;

  // weight frags: wb + kc*3072 + s*512 (ushort offsets), s in {0..5}
  const unsigned short* wb = Wpk + (size_t)wave * 24576 + lane * 8;

  // biases: col is tile-invariant -> hoist (4 VGPR)
  const float br  = b_ih[col]       + b_hh[col];
  const float bz  = b_ih[col + 256] + b_hh[col + 256];
  const float bin = b_ih[col + 512];
  const float bhn = b_hh[col + 512];

  const int t0 = blockIdx.x * (NTILE / 256);   // 18 tiles per block

#define STAGE(T, XS, HS) do {                                            \
    const int _t = (T);                                                  \
    const unsigned short* _xb; const unsigned short* _hb; int _rb;       \
    if (_t < NPRT) { _xb = Xp; _hb = Hbp; _rb = _t * 32; }               \
    else           { _xb = Xo; _hb = Hbo; _rb = (_t - NPRT) * 32; }      \
    const int _R = wave * 2;      /* 2 rows (1 KB) per gload, 16 waves */ \
    gload16(_xb + (size_t)(_rb + _R) * DIMN + lane * 8, (XS) + _R * 256); \
    gload16(_hb + (size_t)(_rb + _R) * DIMN + lane * 8, (HS) + _R * 256); \
  } while (0)

#define COMPUTE(T, XS, HS) do {                                          \
    const int _t = (T);                                                  \
    const float* _hf; float* _out; int _rb;                              \
    if (_t < NPRT) { _hf = Hfp; _out = OUTp; _rb = _t * 32; }            \
    else           { _hf = Hfo; _out = OUTo; _rb = (_t - NPRT) * 32; }   \
    floatx4 ar0={0,0,0,0}, az0={0,0,0,0}, an0={0,0,0,0}, ah0={0,0,0,0};  \
    floatx4 ar1={0,0,0,0}, az1={0,0,0,0}, an1={0,0,0,0}, ah1={0,0,0,0};  \
    _Pragma("unroll")                                                    \
    for (int kc = 0; kc < 8; kc++) {                                     \
      const unsigned short* wk = wb + kc * 3072;                         \
      const int sw = ((kc * 4 + quad) ^ (l16 & 7)) * 8;                  \
      bf16x8 bri = *(const bf16x8*)(wk);                                 \
      bf16x8 bzi = *(const bf16x8*)(wk + 512);                           \
      bf16x8 bni = *(const bf16x8*)(wk + 1024);                          \
      bf16x8 aX0 = *(const bf16x8*)((XS) + l16 * 256 + sw);              \
      bf16x8 aX1 = *(const bf16x8*)((XS) + (16 + l16) * 256 + sw);       \
      ar0 = mfma16(aX0, bri, ar0);  ar1 = mfma16(aX1, bri, ar1);         \
      az0 = mfma16(aX0, bzi, az0);  az1 = mfma16(aX1, bzi, az1);         \
      an0 = mfma16(aX0, bni, an0);  an1 = mfma16(aX1, bni, an1);         \
      bf16x8 brh = *(const bf16x8*)(wk + 1536);                          \
      bf16x8 bzh = *(const bf16x8*)(wk + 2048);                          \
      bf16x8 bnh = *(const bf16x8*)(wk + 2560);                          \
      bf16x8 aH0 = *(const bf16x8*)((HS) + l16 * 256 + sw);              \
      bf16x8 aH1 = *(const bf16x8*)((HS) + (16 + l16) * 256 + sw);       \
      ar0 = mfma16(aH0, brh, ar0);  ar1 = mfma16(aH1, brh, ar1);         \
      az0 = mfma16(aH0, bzh, az0);  az1 = mfma16(aH1, bzh, az1);         \
      ah0 = mfma16(aH0, bnh, ah0);  ah1 = mfma16(aH1, bnh, ah1);         \
    }                                                                    \
    _Pragma("unroll")                                                    \
    for (int v = 0; v < 4; v++) {                                        \
      { const int m = _rb + (quad << 2) + v;                             \
        const size_t idx = (size_t)m * DIMN + col;                       \
        const float r_ = sigmoidf_(ar0[v] + br);                         \
        const float z_ = sigmoidf_(az0[v] + bz);                         \
        const float n_ = tanhf_(an0[v] + bin + r_ * (ah0[v] + bhn));     \
        _out[idx] = (1.0f - z_) * n_ + z_ * _hf[idx]; }                  \
      { const int m = _rb + 16 + (quad << 2) + v;                        \
        const size_t idx = (size_t)m * DIMN + col;                       \
        const float r_ = sigmoidf_(ar1[v] + br);                         \
        const float z_ = sigmoidf_(az1[v] + bz);                         \
        const float n_ = tanhf_(an1[v] + bin + r_ * (ah1[v] + bhn));     \
        _out[idx] = (1.0f - z_) * n_ + z_ * _hf[idx]; }                  \
    }                                                                    \
  } while (0)

  STAGE(t0, Xs0, Hs0);
  __syncthreads();                    // drains stage vmcnt
  #pragma unroll 1
  for (int i = 0; i < NTILE / 256; i += 2) {
    if (i + 1 < NTILE / 256) STAGE(t0 + i + 1, Xs1, Hs1);
    COMPUTE(t0 + i, Xs0, Hs0);
    __syncthreads();
    if (i + 2 < NTILE / 256) STAGE(t0 + i + 2, Xs0, Hs0);
    COMPUTE(t0 + i + 1, Xs1, Hs1);
    __syncthreads();
  }
#undef STAGE
#undef COMPUTE
}

// ---------------------------------------------------------------------------
extern "C" void kernel_launch(void* const* d_in, const int* in_sizes, int n_in,
                              void* d_out, int out_size, void* d_ws, size_t ws_size,
                              hipStream_t stream) {
  const float* x_obj  = (const float*)d_in[0];
  const float* x_pred = (const float*)d_in[1];
  const int*   pairs  = (const int*)d_in[2];
  const float* w_e2v  = (const float*)d_in[3];
  const float* b_e2v  = (const float*)d_in[4];
  const float* w_v2e  = (const float*)d_in[5];
  const float* b_v2e  = (const float*)d_in[6];
  const float* w_ih   = (const float*)d_in[7];
  const float* w_hh   = (const float*)d_in[8];
  const float* b_ih   = (const float*)d_in[9];
  const float* b_hh   = (const float*)d_in[10];

  char* ws = (char*)d_ws;
  size_t off = 0;
  unsigned short* msg   = (unsigned short*)(ws + off); off += (size_t)NOBJ * DIMN * 2;   // 8.4 MB
  unsigned short* xg    = (unsigned short*)(ws + off); off += (size_t)NPAIR * DIMN * 2;  // 67 MB
  unsigned short* hp_bf = (unsigned short*)(ws + off); off += (size_t)NPAIR * DIMN * 2;  // 67 MB
  unsigned short* ho_bf = (unsigned short*)(ws + off); off += (size_t)NOBJ * DIMN * 2;   // 8.4 MB
  unsigned short* wbf   = (unsigned short*)(ws + off); off += (size_t)2 * 768 * 256 * 2; // 786 KB
  float* gbuf = (float*)(ws + off); off += (size_t)NINC * 4;           // 1 MB
  int* row_start = (int*)(ws + off); off += (size_t)(NOBJ + 2) * 4;
  int* entries   = (int*)(ws + off); off += (size_t)NINC * 4;          // 1 MB
  // cnt & cursor only live during CSR build -> alias into msg region
  int* cnt    = (int*)msg;
  int* cursor = (int*)msg + NOBJ;

  float* O = (float*)d_out;                 // objects section
  float* P = O + (size_t)NOBJ * DIMN;       // predicates section

  conv_w<<<192, 256, 0, stream>>>(w_ih, w_hh, wbf);

  // CSR build (pairs are launch-constant; rebuilt every call for graph safety)
  (void)hipMemsetAsync(cnt, 0, NOBJ * sizeof(int), stream);
  hist_kernel<<<NINC / 256, 256, 0, stream>>>(pairs, cnt);
  scan_kernel<<<1, 1024, 0, stream>>>(cnt, row_start, cursor);
  scatter_kernel<<<NINC / 256, 256, 0, stream>>>(pairs, cursor, entries);

  const float* xo_cur = x_obj;
  const float* xp_cur = x_pred;
  for (int s = 0; s < 2; s++) {
    gate_kernel<<<NPAIR / 4, 256, 0, stream>>>(xo_cur, xp_cur, pairs,
                                               w_e2v, b_e2v, w_v2e, b_v2e,
                                               gbuf, xg, hp_bf);
    conv_h<<<NOBJ / 4, 256, 0, stream>>>(xo_cur, ho_bf);
    gather_kernel<<<NOBJ / 4, 256, 0, stream>>>(xp_cur, gbuf, row_start, entries, msg);
    gru_kernel<<<256, 1024, 0, stream>>>(xg, hp_bf, xp_cur, P,
                                         msg, ho_bf, xo_cur, O,
                                         wbf, b_ih, b_hh);
    xo_cur = O; xp_cur = P;
  }
}